// Round 6
// baseline (157.384 us; speedup 1.0000x reference)
//
#include <hip/hip_runtime.h>
#include <math.h>

#define NB    128
#define NG    52
#define NGG   2704          // NG*NG (divisible by 4)
#define NA    3
#define NCLS  15
#define NCH   20
#define NQ    8112          // NA*NGG
#define TOTAL 1038336       // NB*NQ
#define BLK   128
#define CPT   4             // cells per thread (dwordx4 loads)
#define WCELLS 256          // cells per wave
#define BCELLS 512          // cells per block
#define NBLK  (TOTAL/BCELLS) // 2028 (exact)
#define FPW   (WCELLS*NCH)  // 5120 floats staged per wave (20 KB)
#define NQ4   ((FPW-4)/4)   // 1279 f4 stores per wave
#define NPART (NBLK*2)      // 4056 per-wave partials

typedef float f4 __attribute__((ext_vector_type(4)));

// LDS dword-index swizzle: spreads banks for the cell-major write pattern
// while preserving 16B blocks (f4 read index becomes q ^ ((q>>5)&7)).
__device__ __forceinline__ int swz(int L) { return L ^ (((L >> 7) & 7) << 2); }

// ---- main kernel: 4 cells/thread, f4 global loads, wave-private restage ----
__global__ __launch_bounds__(BLK) void main_kernel(const float* __restrict__ x,
                                                   const float* __restrict__ labels,
                                                   float* __restrict__ out,
                                                   float* __restrict__ partials) {
    __shared__ __align__(16) float sm[2][FPW];   // 40 KB: private row per wave

    int t = threadIdx.x;
    int w = t >> 6;                    // wave in block
    int l = t & 63;                    // lane
    int cell0 = (blockIdx.x * BLK + t) * CPT;   // first of 4 consecutive cells
    int b  = cell0 / NQ;               // fixed for all 4 cells (NQ%4==0)
    int r  = cell0 - b * NQ;
    int a  = r / NGG;                  // fixed (NGG%4==0)
    int ji0 = r - a * NGG;             // multiple of 4

    // 20 dwordx4 loads: 16 B/lane, covers 4 cells x 20 channels
    const f4* __restrict__ xp4 =
        (const f4*)(x + ((size_t)(b*60 + a*20)) * NGG) + (ji0 >> 2);
    f4 z4[NCH];
    #pragma unroll
    for (int c = 0; c < NCH; c++) z4[c] = xp4[c * (NGG/4)];

    // ---- per-thread target logic (b,a fixed) ----
    float gx = labels[b*5+0] * (float)NG;
    float gy = labels[b*5+1] * (float)NG;
    float gw = labels[b*5+2] * (float)NG;
    float gh = labels[b*5+3] * (float)NG;
    int  gcls = (int)labels[b*5+4];
    int gi = (int)gx, gj = (int)gy;
    int target = gj * NG + gi;
    float gwgh = gw * gh;
    float i0 = fminf(12.0f,   gw) * fminf(28.75f,  gh);
    float i1 = fminf(9.875f,  gw) * fminf(23.25f,  gh);
    float i2 = fminf(10.125f, gw) * fminf(16.625f, gh);
    float iou0 = i0 / (345.0f      + 1e-16f + gwgh - i0);
    float iou1 = i1 / (229.59375f  + 1e-16f + gwgh - i1);
    float iou2 = i2 / (168.328125f + 1e-16f + gwgh - i2);
    int best = 0; float bv = iou0;
    if (iou1 > bv) { best = 1; bv = iou1; }
    if (iou2 > bv) { best = 2; bv = iou2; }
    float ioua = (a == 0) ? iou0 : ((a == 1) ? iou1 : iou2);
    bool isbest = (a == best);

    float tsum = 0.0f;
    float* __restrict__ smw = sm[w];

    #pragma unroll
    for (int i = 0; i < CPT; i++) {
        float z[NCH];
        #pragma unroll
        for (int c = 0; c < NCH; c++) z[c] = z4[c][i];

        float v[NCH];
        float conf = 1.0f / (1.0f + __expf(-z[4]));
        v[0] = 8.0f / (1.0f + __expf(-z[0]));
        v[1] = 8.0f / (1.0f + __expf(-z[1]));
        v[2] = 8.0f * z[2];
        v[3] = 8.0f * z[3];
        v[4] = conf;
        float m = z[5];
        #pragma unroll
        for (int c = 6; c < NCH; c++) m = fmaxf(m, z[c]);
        float s = 0.0f;
        #pragma unroll
        for (int c = 0; c < NCLS; c++) { v[5+c] = __expf(z[5+c] - m); s += v[5+c]; }
        float inv = 1.0f / s;
        #pragma unroll
        for (int c = 0; c < NCLS; c++) v[5+c] *= inv;

        bool at_t = (ji0 + i == target);
        // noobj BCE (x100), skipped where reference zeroes the mask
        if (!(at_t && (isbest || ioua > 0.5f)))
            tsum += -100.0f * fmaxf(__logf(1.0f - conf), -100.0f);
        // obj terms at the best-anchor target cell (rare)
        if (at_t && isbest) {
            tsum += -fmaxf(__logf(conf), -100.0f);
            float txv = gx - (float)gi;
            float tyv = gy - (float)gj;
            float abw = (best == 0) ? 12.0f  : ((best == 1) ? 9.875f : 10.125f);
            float abh = (best == 0) ? 28.75f : ((best == 1) ? 23.25f : 16.625f);
            float twv = __logf(gw / abw + 1e-16f);
            float thv = __logf(gh / abh + 1e-16f);
            tsum += fabsf(v[0]*0.125f - txv) + fabsf(v[1]*0.125f - tyv)
                  + fabsf(v[2]*0.125f - twv) + fabsf(v[3]*0.125f - thv);
            #pragma unroll
            for (int c = 0; c < NCLS; c++) {
                float p = v[5+c];
                tsum += (c == gcls) ? -fmaxf(__logf(p),        -100.0f)
                                    : -fmaxf(__logf(1.0f - p), -100.0f);
            }
        }

        // shifted + swizzled LDS restage (wrap only lane 0, i==0, c<3)
        int base = (l * CPT + i) * NCH - 3;
        #pragma unroll
        for (int c = 0; c < NCH; c++) {
            int L = base + c;
            if (L < 0) L += FPW;
            smw[swz(L)] = v[c];
        }
    }

    // wave reduce loss partial
    #pragma unroll
    for (int off = 32; off > 0; off >>= 1) tsum += __shfl_down(tsum, off, 64);

    // wave-synchronous readback (no barriers in this kernel)
    int wcell0 = blockIdx.x * BCELLS + w * WCELLS;
    size_t gf = 1 + (size_t)wcell0 * NCH;           // wave's first out float
    f4* __restrict__ op = (f4*)(out + gf + 3);      // 16B-aligned
    const f4* __restrict__ sp = (const f4*)smw;
    #pragma unroll
    for (int k = 0; k < 20; k++) {
        int q = k * 64 + l;
        if (q < NQ4) {
            f4 val = sp[q ^ ((q >> 5) & 7)];        // swizzled f4 read
            __builtin_nontemporal_store(val, &op[q]);
        }
    }
    if (l == 0) {
        out[gf + 0]       = smw[swz(FPW - 3)];      // head 3 floats (wrapped)
        out[gf + 1]       = smw[swz(FPW - 2)];
        out[gf + 2]       = smw[swz(FPW - 1)];
        out[gf + FPW - 1] = smw[swz(FPW - 4)];      // tail scalar
        partials[blockIdx.x * 2 + w] = tsum;
    }
}

// ---- finish: deterministic reduction of per-wave partials ----
__global__ __launch_bounds__(1024) void finish_kernel(const float* __restrict__ partials,
                                                      float* __restrict__ out) {
    int t = threadIdx.x;
    float s = 0.0f;
    #pragma unroll
    for (int k = 0; k < NPART/1024 + 1; k++) {
        int q = k * 1024 + t;
        if (q < NPART) s += partials[q];
    }
    __shared__ float red[1024];
    red[t] = s;
    __syncthreads();
    for (int k = 512; k > 0; k >>= 1) {
        if (t < k) red[t] += red[t + k];
        __syncthreads();
    }
    if (t == 0) out[0] = red[0];
}

extern "C" void kernel_launch(void* const* d_in, const int* in_sizes, int n_in,
                              void* d_out, int out_size, void* d_ws, size_t ws_size,
                              hipStream_t stream) {
    const float* x      = (const float*)d_in[0];
    const float* labels = (const float*)d_in[1];
    float* out = (float*)d_out;
    float* ws  = (float*)d_ws;

    hipLaunchKernelGGL(main_kernel,   dim3(NBLK), dim3(BLK),  0, stream, x, labels, out, ws);
    hipLaunchKernelGGL(finish_kernel, dim3(1),    dim3(1024), 0, stream, ws, out);
}

// Round 9
// 155.360 us; speedup vs baseline: 1.0130x; 1.0130x over previous
//
#include <hip/hip_runtime.h>
#include <math.h>

#define NB    128
#define NG    52
#define NGG   2704          // NG*NG
#define NA    3
#define NCLS  15
#define NCH   20
#define NQ    8112          // NA*NGG
#define TOTAL 1038336       // NB*NQ
#define BLK   256
#define NBLK  (TOTAL/BLK)   // 4056 (exact)
#define WPB   (BLK/64)      // 4 waves per block
#define FPW   (64*NCH)      // 1280 floats staged per wave
#define NPART (NBLK*WPB)    // 16224 per-wave partials

typedef float f4 __attribute__((ext_vector_type(4)));

// ---- main kernel: transform + loss terms; wave-synchronous restage, NO barriers
__global__ __launch_bounds__(BLK) void main_kernel(const float* __restrict__ x,
                                                   const float* __restrict__ labels,
                                                   float* __restrict__ out,
                                                   float* __restrict__ partials) {
    __shared__ __align__(16) float sm[WPB][FPW];   // private row per wave

    int t = threadIdx.x;
    int w = t >> 6;                   // wave id in block
    int l = t & 63;                   // lane
    int cell = blockIdx.x * BLK + t;  // one cell per thread
    int b  = cell / NQ;
    int r  = cell - b * NQ;
    int a  = r / NGG;
    int ji = r - a * NGG;

    const float* __restrict__ xp = x + ((size_t)(b*60 + a*20)) * NGG + ji;
    float z[NCH];
    #pragma unroll
    for (int c = 0; c < NCH; c++) z[c] = xp[c * NGG];

    float v[NCH];
    float conf = 1.0f / (1.0f + __expf(-z[4]));
    v[0] = 8.0f / (1.0f + __expf(-z[0]));
    v[1] = 8.0f / (1.0f + __expf(-z[1]));
    v[2] = 8.0f * z[2];
    v[3] = 8.0f * z[3];
    v[4] = conf;
    float m = z[5];
    #pragma unroll
    for (int c = 6; c < NCH; c++) m = fmaxf(m, z[c]);
    float s = 0.0f;
    #pragma unroll
    for (int c = 0; c < NCLS; c++) { v[5+c] = __expf(z[5+c] - m); s += v[5+c]; }
    float inv = 1.0f / s;
    #pragma unroll
    for (int c = 0; c < NCLS; c++) v[5+c] *= inv;

    // ---- per-batch target logic ----
    float gx = labels[b*5+0] * (float)NG;
    float gy = labels[b*5+1] * (float)NG;
    float gw = labels[b*5+2] * (float)NG;
    float gh = labels[b*5+3] * (float)NG;
    int  gcls = (int)labels[b*5+4];
    int gi = (int)gx, gj = (int)gy;
    float gwgh = gw * gh;
    float i0 = fminf(12.0f,   gw) * fminf(28.75f,  gh);
    float i1 = fminf(9.875f,  gw) * fminf(23.25f,  gh);
    float i2 = fminf(10.125f, gw) * fminf(16.625f, gh);
    float iou0 = i0 / (345.0f      + 1e-16f + gwgh - i0);   // 12*28.75
    float iou1 = i1 / (229.59375f  + 1e-16f + gwgh - i1);   // 9.875*23.25
    float iou2 = i2 / (168.328125f + 1e-16f + gwgh - i2);   // 10.125*16.625
    int best = 0; float bv = iou0;
    if (iou1 > bv) { best = 1; bv = iou1; }
    if (iou2 > bv) { best = 2; bv = iou2; }
    float ioua = (a == 0) ? iou0 : ((a == 1) ? iou1 : iou2);
    bool at_t   = (ji == gj * NG + gi);
    bool isbest = (a == best);

    float tsum = 0.0f;
    // noobj BCE term (x100), skipped where reference zeroes the noobj mask
    if (!(at_t && (isbest || ioua > 0.5f)))
        tsum = -100.0f * fmaxf(__logf(1.0f - conf), -100.0f);
    // obj terms at the best-anchor target cell
    if (at_t && isbest) {
        tsum += -fmaxf(__logf(conf), -100.0f);            // conf BCE, t=1
        float txv = gx - (float)gi;
        float tyv = gy - (float)gj;
        float abw = (best == 0) ? 12.0f  : ((best == 1) ? 9.875f : 10.125f);
        float abh = (best == 0) ? 28.75f : ((best == 1) ? 23.25f : 16.625f);
        float twv = __logf(gw / abw + 1e-16f);
        float thv = __logf(gh / abh + 1e-16f);
        tsum += fabsf(v[0]*0.125f - txv) + fabsf(v[1]*0.125f - tyv)
              + fabsf(v[2]*0.125f - twv) + fabsf(v[3]*0.125f - thv);
        #pragma unroll
        for (int c = 0; c < NCLS; c++) {
            float p = v[5+c];
            tsum += (c == gcls) ? -fmaxf(__logf(p),        -100.0f)
                                : -fmaxf(__logf(1.0f - p), -100.0f);
        }
    }

    // per-wave shifted LDS restage (wrap only for lane 0, c<3)
    float* __restrict__ smw = sm[w];
    int base = l * NCH - 3;
    #pragma unroll
    for (int c = 0; c < NCH; c++) {
        int L = base + c;
        if (L < 0) L += FPW;
        smw[L] = v[c];
    }

    // wave reduce loss partial (lane 0 ends with the wave sum)
    #pragma unroll
    for (int off = 32; off > 0; off >>= 1) tsum += __shfl_down(tsum, off, 64);

    // wave-synchronous readback: lanes are lockstep; compiler orders ds ops
    // (lgkmcnt drain) -- NO __syncthreads anywhere in this kernel.
    int cell0 = blockIdx.x * BLK + w * 64;                 // wave's first cell
    size_t gf = 1 + (size_t)cell0 * NCH;                   // first out float of wave region
    f4* __restrict__ op = (f4*)(out + gf + 3);             // 16B-aligned (gf+3 = 4+cell0*20)
    const f4* __restrict__ sp = (const f4*)smw;
    #pragma unroll
    for (int k = 0; k < 5; k++) {
        int q = k * 64 + l;
        if (q < (FPW - 4) / 4) __builtin_nontemporal_store(sp[q], &op[q]);  // 319 f4
    }
    if (l == 0) {
        out[gf + 0]       = smw[FPW - 3];   // head 3 floats (wrapped)
        out[gf + 1]       = smw[FPW - 2];
        out[gf + 2]       = smw[FPW - 1];
        out[gf + FPW - 1] = smw[FPW - 4];   // tail scalar
        partials[blockIdx.x * WPB + w] = tsum;
    }
}

// ---- finish: deterministic reduction of 16224 per-wave partials ----
__global__ __launch_bounds__(1024) void finish_kernel(const float* __restrict__ partials,
                                                      float* __restrict__ out) {
    int t = threadIdx.x;   // 1024 threads
    float s = 0.0f;
    #pragma unroll
    for (int k = 0; k < NPART/1024 + 1; k++) {
        int q = k * 1024 + t;
        if (q < NPART) s += partials[q];
    }
    __shared__ float red[1024];
    red[t] = s;
    __syncthreads();
    for (int k = 512; k > 0; k >>= 1) {
        if (t < k) red[t] += red[t + k];
        __syncthreads();
    }
    if (t == 0) out[0] = red[0];
}

extern "C" void kernel_launch(void* const* d_in, const int* in_sizes, int n_in,
                              void* d_out, int out_size, void* d_ws, size_t ws_size,
                              hipStream_t stream) {
    const float* x      = (const float*)d_in[0];
    const float* labels = (const float*)d_in[1];
    float* out = (float*)d_out;
    float* ws  = (float*)d_ws;

    hipLaunchKernelGGL(main_kernel,   dim3(NBLK), dim3(BLK),  0, stream, x, labels, out, ws);
    hipLaunchKernelGGL(finish_kernel, dim3(1),    dim3(1024), 0, stream, ws, out);
}

// Round 10
// 152.374 us; speedup vs baseline: 1.0329x; 1.0196x over previous
//
#include <hip/hip_runtime.h>
#include <math.h>

#define NB    128
#define NG    52
#define NGG   2704          // NG*NG
#define NA    3
#define NCLS  15
#define NCH   20
#define NQ    8112          // NA*NGG
#define TOTAL 1038336       // NB*NQ
#define BLK   256
#define NBLK  (TOTAL/BLK)   // 4056 (exact)
#define WPB   (BLK/64)      // 4 waves per block
#define FPW   (64*NCH)      // 1280 floats staged per wave
#define NPART (NBLK*WPB)    // 16224 per-wave partials

typedef float f4 __attribute__((ext_vector_type(4)));

// ---- main kernel: transform + loss terms; wave-synchronous restage, NO barriers
__global__ __launch_bounds__(BLK) void main_kernel(const float* __restrict__ x,
                                                   const float* __restrict__ labels,
                                                   float* __restrict__ out,
                                                   float* __restrict__ partials) {
    __shared__ __align__(16) float sm[WPB][FPW];   // private row per wave

    int t = threadIdx.x;
    int w = t >> 6;                   // wave id in block
    int l = t & 63;                   // lane
    int cell = blockIdx.x * BLK + t;  // one cell per thread
    int b  = cell / NQ;
    int r  = cell - b * NQ;
    int a  = r / NGG;
    int ji = r - a * NGG;

    const float* __restrict__ xp = x + ((size_t)(b*60 + a*20)) * NGG + ji;
    float z[NCH];
    #pragma unroll
    for (int c = 0; c < NCH; c++) z[c] = xp[c * NGG];

    float v[NCH];
    float conf = 1.0f / (1.0f + __expf(-z[4]));
    v[0] = 8.0f / (1.0f + __expf(-z[0]));
    v[1] = 8.0f / (1.0f + __expf(-z[1]));
    v[2] = 8.0f * z[2];
    v[3] = 8.0f * z[3];
    v[4] = conf;
    float m = z[5];
    #pragma unroll
    for (int c = 6; c < NCH; c++) m = fmaxf(m, z[c]);
    float s = 0.0f;
    #pragma unroll
    for (int c = 0; c < NCLS; c++) { v[5+c] = __expf(z[5+c] - m); s += v[5+c]; }
    float inv = 1.0f / s;
    #pragma unroll
    for (int c = 0; c < NCLS; c++) v[5+c] *= inv;

    // ---- per-batch target logic ----
    float gx = labels[b*5+0] * (float)NG;
    float gy = labels[b*5+1] * (float)NG;
    float gw = labels[b*5+2] * (float)NG;
    float gh = labels[b*5+3] * (float)NG;
    int  gcls = (int)labels[b*5+4];
    int gi = (int)gx, gj = (int)gy;
    float gwgh = gw * gh;
    float i0 = fminf(12.0f,   gw) * fminf(28.75f,  gh);
    float i1 = fminf(9.875f,  gw) * fminf(23.25f,  gh);
    float i2 = fminf(10.125f, gw) * fminf(16.625f, gh);
    float iou0 = i0 / (345.0f      + 1e-16f + gwgh - i0);   // 12*28.75
    float iou1 = i1 / (229.59375f  + 1e-16f + gwgh - i1);   // 9.875*23.25
    float iou2 = i2 / (168.328125f + 1e-16f + gwgh - i2);   // 10.125*16.625
    int best = 0; float bv = iou0;
    if (iou1 > bv) { best = 1; bv = iou1; }
    if (iou2 > bv) { best = 2; bv = iou2; }
    float ioua = (a == 0) ? iou0 : ((a == 1) ? iou1 : iou2);
    bool at_t   = (ji == gj * NG + gi);
    bool isbest = (a == best);

    float tsum = 0.0f;
    // noobj BCE term (x100), skipped where reference zeroes the noobj mask
    if (!(at_t && (isbest || ioua > 0.5f)))
        tsum = -100.0f * fmaxf(__logf(1.0f - conf), -100.0f);
    // obj terms at the best-anchor target cell
    if (at_t && isbest) {
        tsum += -fmaxf(__logf(conf), -100.0f);            // conf BCE, t=1
        float txv = gx - (float)gi;
        float tyv = gy - (float)gj;
        float abw = (best == 0) ? 12.0f  : ((best == 1) ? 9.875f : 10.125f);
        float abh = (best == 0) ? 28.75f : ((best == 1) ? 23.25f : 16.625f);
        float twv = __logf(gw / abw + 1e-16f);
        float thv = __logf(gh / abh + 1e-16f);
        tsum += fabsf(v[0]*0.125f - txv) + fabsf(v[1]*0.125f - tyv)
              + fabsf(v[2]*0.125f - twv) + fabsf(v[3]*0.125f - thv);
        #pragma unroll
        for (int c = 0; c < NCLS; c++) {
            float p = v[5+c];
            tsum += (c == gcls) ? -fmaxf(__logf(p),        -100.0f)
                                : -fmaxf(__logf(1.0f - p), -100.0f);
        }
    }

    // per-wave shifted LDS restage (wrap only for lane 0, c<3)
    float* __restrict__ smw = sm[w];
    int base = l * NCH - 3;
    #pragma unroll
    for (int c = 0; c < NCH; c++) {
        int L = base + c;
        if (L < 0) L += FPW;
        smw[L] = v[c];
    }

    // wave reduce loss partial (lane 0 ends with the wave sum)
    #pragma unroll
    for (int off = 32; off > 0; off >>= 1) tsum += __shfl_down(tsum, off, 64);

    // wave-synchronous readback: lanes are lockstep; compiler orders ds ops
    // (lgkmcnt drain) -- NO __syncthreads anywhere in this kernel.
    int cell0 = blockIdx.x * BLK + w * 64;                 // wave's first cell
    size_t gf = 1 + (size_t)cell0 * NCH;                   // first out float of wave region
    f4* __restrict__ op = (f4*)(out + gf + 3);             // 16B-aligned (gf+3 = 4+cell0*20)
    const f4* __restrict__ sp = (const f4*)smw;
    #pragma unroll
    for (int k = 0; k < 5; k++) {
        int q = k * 64 + l;
        if (q < (FPW - 4) / 4) op[q] = sp[q];   // PLAIN stores this round (NT A/B)
    }
    if (l == 0) {
        out[gf + 0]       = smw[FPW - 3];   // head 3 floats (wrapped)
        out[gf + 1]       = smw[FPW - 2];
        out[gf + 2]       = smw[FPW - 1];
        out[gf + FPW - 1] = smw[FPW - 4];   // tail scalar
        partials[blockIdx.x * WPB + w] = tsum;
    }
}

// ---- finish: deterministic reduction of 16224 per-wave partials ----
__global__ __launch_bounds__(1024) void finish_kernel(const float* __restrict__ partials,
                                                      float* __restrict__ out) {
    int t = threadIdx.x;   // 1024 threads
    float s = 0.0f;
    #pragma unroll
    for (int k = 0; k < NPART/1024 + 1; k++) {
        int q = k * 1024 + t;
        if (q < NPART) s += partials[q];
    }
    __shared__ float red[1024];
    red[t] = s;
    __syncthreads();
    for (int k = 512; k > 0; k >>= 1) {
        if (t < k) red[t] += red[t + k];
        __syncthreads();
    }
    if (t == 0) out[0] = red[0];
}

extern "C" void kernel_launch(void* const* d_in, const int* in_sizes, int n_in,
                              void* d_out, int out_size, void* d_ws, size_t ws_size,
                              hipStream_t stream) {
    const float* x      = (const float*)d_in[0];
    const float* labels = (const float*)d_in[1];
    float* out = (float*)d_out;
    float* ws  = (float*)d_ws;

    hipLaunchKernelGGL(main_kernel,   dim3(NBLK), dim3(BLK),  0, stream, x, labels, out, ws);
    hipLaunchKernelGGL(finish_kernel, dim3(1),    dim3(1024), 0, stream, ws, out);
}

// Round 11
// 151.980 us; speedup vs baseline: 1.0356x; 1.0026x over previous
//
#include <hip/hip_runtime.h>
#include <math.h>

#define NB    128
#define NG    52
#define NGG   2704          // NG*NG = 42*64 + 16
#define NA    3
#define NCLS  15
#define NCH   20
#define TOTAL 1038336
#define PLANES (NB*NA)      // 384 (b,a) planes
#define WVP   43            // wave-slots per plane (42 full + 16-cell tail)
#define NSLOT (PLANES*WVP)  // 16512 wave-slots
#define WPB   4
#define BLK   256
#define NBLK2 (NSLOT/WPB)   // 4128 blocks (exact)
#define FPW   (64*NCH)      // 1280 floats LDS per wave (20 KB/block)
#define NPART NSLOT

typedef float f4 __attribute__((ext_vector_type(4)));

// async global->LDS DMA, 4 B per lane: lane l's word lands at lptr + l*4
__device__ __forceinline__ void gload_lds(const float* g, float* l) {
    __builtin_amdgcn_global_load_lds(
        (const __attribute__((address_space(1))) void*)g,
        (__attribute__((address_space(3))) void*)l, 4, 0, 0);
}

// ---- main kernel: wave-uniform planes, global_load_lds staging, no barriers
__global__ __launch_bounds__(BLK) void main_kernel(const float* __restrict__ x,
                                                   const float* __restrict__ labels,
                                                   float* __restrict__ out,
                                                   float* __restrict__ partials) {
    __shared__ __align__(16) float sm[WPB][FPW];

    int t = threadIdx.x;
    int w = t >> 6;                    // wave in block
    int l = t & 63;                    // lane
    int wslot = blockIdx.x * WPB + w;  // global wave-slot
    int p  = wslot / WVP;              // plane id (wave-uniform)
    int k  = wslot - p * WVP;          // 64-cell chunk within plane
    int b  = p / 3;                    // batch   (wave-uniform -> scalar)
    int a  = p - b * 3;                // anchor  (wave-uniform -> scalar)
    int ji0 = k * 64;
    int ji  = ji0 + l;
    bool active = (ji < NGG);
    int NACT = (NGG - ji0 < 64) ? (NGG - ji0) : 64;   // 64 or 16, uniform
    int FACT = NACT * NCH;                            // 1280 or 320

    float* __restrict__ smw = sm[w];
    const float* __restrict__ xplane = x + ((size_t)(b*60 + a*20)) * NGG + ji0;

    // ---- stage: 20 async DMA issues, channel c -> smw[c*64 .. c*64+63]
    if (active) {
        #pragma unroll
        for (int c = 0; c < NCH; c++)
            gload_lds(xplane + c * NGG + l, &smw[c * 64]);
    }
    asm volatile("s_waitcnt vmcnt(0)" ::: "memory");
    __builtin_amdgcn_sched_barrier(0);

    // ---- read own cell's 20 channels (bank-conflict-free: stride 256 B)
    float z[NCH];
    #pragma unroll
    for (int c = 0; c < NCH; c++) z[c] = smw[c * 64 + l];

    float v[NCH];
    float conf = 1.0f / (1.0f + __expf(-z[4]));
    v[0] = 8.0f / (1.0f + __expf(-z[0]));
    v[1] = 8.0f / (1.0f + __expf(-z[1]));
    v[2] = 8.0f * z[2];
    v[3] = 8.0f * z[3];
    v[4] = conf;
    float m = z[5];
    #pragma unroll
    for (int c = 6; c < NCH; c++) m = fmaxf(m, z[c]);
    float s = 0.0f;
    #pragma unroll
    for (int c = 0; c < NCLS; c++) { v[5+c] = __expf(z[5+c] - m); s += v[5+c]; }
    float inv = 1.0f / s;
    #pragma unroll
    for (int c = 0; c < NCLS; c++) v[5+c] *= inv;

    // ---- per-batch target logic (b,a wave-uniform -> scalarizes) ----
    float gx = labels[b*5+0] * (float)NG;
    float gy = labels[b*5+1] * (float)NG;
    float gw = labels[b*5+2] * (float)NG;
    float gh = labels[b*5+3] * (float)NG;
    int  gcls = (int)labels[b*5+4];
    int gi = (int)gx, gj = (int)gy;
    float gwgh = gw * gh;
    float i0 = fminf(12.0f,   gw) * fminf(28.75f,  gh);
    float i1 = fminf(9.875f,  gw) * fminf(23.25f,  gh);
    float i2 = fminf(10.125f, gw) * fminf(16.625f, gh);
    float iou0 = i0 / (345.0f      + 1e-16f + gwgh - i0);
    float iou1 = i1 / (229.59375f  + 1e-16f + gwgh - i1);
    float iou2 = i2 / (168.328125f + 1e-16f + gwgh - i2);
    int best = 0; float bv = iou0;
    if (iou1 > bv) { best = 1; bv = iou1; }
    if (iou2 > bv) { best = 2; bv = iou2; }
    float ioua = (a == 0) ? iou0 : ((a == 1) ? iou1 : iou2);
    bool at_t   = (ji == gj * NG + gi);
    bool isbest = (a == best);

    float tsum = 0.0f;
    if (active) {
        // noobj BCE (x100), skipped where reference zeroes the mask
        if (!(at_t && (isbest || ioua > 0.5f)))
            tsum = -100.0f * fmaxf(__logf(1.0f - conf), -100.0f);
        // obj terms at the best-anchor target cell
        if (at_t && isbest) {
            tsum += -fmaxf(__logf(conf), -100.0f);
            float txv = gx - (float)gi;
            float tyv = gy - (float)gj;
            float abw = (best == 0) ? 12.0f  : ((best == 1) ? 9.875f : 10.125f);
            float abh = (best == 0) ? 28.75f : ((best == 1) ? 23.25f : 16.625f);
            float twv = __logf(gw / abw + 1e-16f);
            float thv = __logf(gh / abh + 1e-16f);
            tsum += fabsf(v[0]*0.125f - txv) + fabsf(v[1]*0.125f - tyv)
                  + fabsf(v[2]*0.125f - twv) + fabsf(v[3]*0.125f - thv);
            #pragma unroll
            for (int c = 0; c < NCLS; c++) {
                float pc = v[5+c];
                tsum += (c == gcls) ? -fmaxf(__logf(pc),        -100.0f)
                                    : -fmaxf(__logf(1.0f - pc), -100.0f);
            }
        }
    }

    // ---- restage to shifted out-layout (reuses stage LDS; reads all done)
    asm volatile("s_waitcnt lgkmcnt(0)" ::: "memory");
    if (active) {
        int base = l * NCH - 3;
        #pragma unroll
        for (int c = 0; c < NCH; c++) {
            int L = base + c;
            if (L < 0) L += FPW;               // only lane 0, c<3
            smw[L] = v[c];
        }
    }

    // wave reduce loss partial (inactive lanes contribute 0)
    #pragma unroll
    for (int off = 32; off > 0; off >>= 1) tsum += __shfl_down(tsum, off, 64);

    // ---- wave-synchronous readback + coalesced f4 stores ----
    int NQ4w = (FACT - 4) / 4;                 // 319 or 79, wave-uniform
    int cell0 = p * NGG + ji0;                 // wave's first output cell
    size_t gf = 1 + (size_t)cell0 * NCH;       // cell0*20 % 4 == 0 -> aligned
    f4* __restrict__ op = (f4*)(out + gf + 3);
    const f4* __restrict__ sp = (const f4*)smw;
    #pragma unroll
    for (int kk = 0; kk < 5; kk++) {
        int q = kk * 64 + l;
        if (q < NQ4w) op[q] = sp[q];
    }
    if (l == 0) {
        out[gf + 0]        = smw[FPW - 3];     // wrapped head 3 floats
        out[gf + 1]        = smw[FPW - 2];
        out[gf + 2]        = smw[FPW - 1];
        out[gf + FACT - 1] = smw[FACT - 4];    // tail scalar of wave region
        partials[wslot] = tsum;
    }
}

// ---- finish: deterministic reduction of 16512 per-wave partials ----
__global__ __launch_bounds__(1024) void finish_kernel(const float* __restrict__ partials,
                                                      float* __restrict__ out) {
    int t = threadIdx.x;
    float s = 0.0f;
    #pragma unroll
    for (int k = 0; k < NPART/1024 + 1; k++) {
        int q = k * 1024 + t;
        if (q < NPART) s += partials[q];
    }
    __shared__ float red[1024];
    red[t] = s;
    __syncthreads();
    for (int k = 512; k > 0; k >>= 1) {
        if (t < k) red[t] += red[t + k];
        __syncthreads();
    }
    if (t == 0) out[0] = red[0];
}

extern "C" void kernel_launch(void* const* d_in, const int* in_sizes, int n_in,
                              void* d_out, int out_size, void* d_ws, size_t ws_size,
                              hipStream_t stream) {
    const float* x      = (const float*)d_in[0];
    const float* labels = (const float*)d_in[1];
    float* out = (float*)d_out;
    float* ws  = (float*)d_ws;

    hipLaunchKernelGGL(main_kernel,   dim3(NBLK2), dim3(BLK),  0, stream, x, labels, out, ws);
    hipLaunchKernelGGL(finish_kernel, dim3(1),     dim3(1024), 0, stream, ws, out);
}